// Round 3
// baseline (830.151 us; speedup 1.0000x reference)
//
#include <hip/hip_runtime.h>
#include <math.h>

// ---------- config ----------
#define T_TOK 4096
#define DIM   2048
#define NEXP  32
#define TOPK  4
#define CAP   160          // ceil(1.25*4096/32)
#define ECAP  (NEXP*CAP)   // 5120
#define ISZ   1024         // moe intermediate
#define ISH   2048         // shared intermediate (I*NSH)

typedef short bf16x8 __attribute__((ext_vector_type(8)));
typedef float f32x4  __attribute__((ext_vector_type(4)));

__device__ __forceinline__ unsigned int f2bf(float f){
  union { float f; unsigned int u; } v; v.f = f;
  return (v.u + 0x7fffu + ((v.u >> 16) & 1u)) >> 16;   // RNE
}

// async global->LDS, 16B/lane; LDS base wave-uniform (HW adds lane*16), global addr per-lane
#define GLOAD16(g, l) __builtin_amdgcn_global_load_lds( \
    (const __attribute__((address_space(1))) unsigned int*)(g), \
    (__attribute__((address_space(3))) unsigned int*)(l), 16, 0, 0)

// ---------- fp32 -> bf16 convert ----------
__global__ __launch_bounds__(256) void cvt_k(const float* __restrict__ in,
                                             unsigned short* __restrict__ out, int n8){
  int i = blockIdx.x*256 + threadIdx.x;
  if (i >= n8) return;
  const float4 a = *(const float4*)&in[(size_t)i*8];
  const float4 b = *(const float4*)&in[(size_t)i*8 + 4];
  uint4 v;
  v.x = f2bf(a.x) | (f2bf(a.y) << 16);
  v.y = f2bf(a.z) | (f2bf(a.w) << 16);
  v.z = f2bf(b.x) | (f2bf(b.y) << 16);
  v.w = f2bf(b.z) | (f2bf(b.w) << 16);
  *(uint4*)&out[(size_t)i*8] = v;
}

// ---------- router: fp64 logits, exact top-k semantics ----------
__global__ __launch_bounds__(256) void router_k(const float* __restrict__ x,
                                                const float* __restrict__ rw,
                                                const float* __restrict__ eb,
                                                int* __restrict__ tki,
                                                float* __restrict__ tkw){
  __shared__ float  xs[4][DIM];
  __shared__ double ssh[4][NEXP];
  const int tb = blockIdx.x * 4;
  const int tid = threadIdx.x;
  for (int i = tid; i < 4*(DIM/4); i += 256){
    int t = i >> 9, c = (i & 511) << 2;
    *(float4*)&xs[t][c] = *(const float4*)&x[(size_t)(tb + t)*DIM + c];
  }
  __syncthreads();
  const int lane = tid & 63, wv = tid >> 6;
  for (int ei = 0; ei < 8; ++ei){
    int e = wv*8 + ei;
    double a0=0, a1=0, a2=0, a3=0;
    for (int d = lane; d < DIM; d += 64){
      double w = (double)rw[(size_t)e*DIM + d];
      a0 += (double)xs[0][d] * w;
      a1 += (double)xs[1][d] * w;
      a2 += (double)xs[2][d] * w;
      a3 += (double)xs[3][d] * w;
    }
    for (int off = 32; off; off >>= 1){
      a0 += __shfl_down(a0, off);
      a1 += __shfl_down(a1, off);
      a2 += __shfl_down(a2, off);
      a3 += __shfl_down(a3, off);
    }
    if (lane == 0){ ssh[0][e]=a0; ssh[1][e]=a1; ssh[2][e]=a2; ssh[3][e]=a3; }
  }
  __syncthreads();
  if (tid < 4){
    const int t = tid;
    double s[NEXP], sc[NEXP];
    for (int e = 0; e < NEXP; ++e){
      double sig = 1.0 / (1.0 + exp(-ssh[t][e]));
      s[e] = sig; sc[e] = sig + (double)eb[e];
    }
    double gsc[8];
    for (int g = 0; g < 8; ++g){
      double b0=sc[g*4],b1=sc[g*4+1],b2=sc[g*4+2],b3=sc[g*4+3];
      double h1=fmax(b0,b1), l1=fmin(b0,b1);
      double h2=fmax(b2,b3), l2=fmin(b2,b3);
      double top = fmax(h1,h2);
      double sec = fmax(fmin(h1,h2), (h1 >= h2) ? l1 : l2);
      gsc[g] = top + sec;
    }
    int gsel = 0;
    for (int r = 0; r < 3; ++r){
      int bi = -1; double bv = -1e300;
      for (int g = 0; g < 8; ++g)
        if (!((gsel >> g) & 1) && gsc[g] > bv){ bv = gsc[g]; bi = g; }
      gsel |= 1 << bi;
    }
    double mval[NEXP];
    for (int e = 0; e < NEXP; ++e)
      mval[e] = ((gsel >> (e >> 2)) & 1) ? sc[e] : 0.0;
    int idx4[4]; double wsum = 0.0, wv4[4];
    for (int r = 0; r < 4; ++r){
      int bi = -1; double bv = -1e300;
      for (int e = 0; e < NEXP; ++e)
        if (mval[e] > bv){ bv = mval[e]; bi = e; }
      idx4[r] = bi; mval[bi] = -1e300;
      wv4[r] = s[bi]; wsum += wv4[r];
    }
    const int gt = tb + t;
    for (int r = 0; r < 4; ++r){
      tki[gt*4 + r] = idx4[r];
      tkw[gt*4 + r] = (float)(wv4[r] / (wsum + 1e-20) * 2.5);
    }
  }
}

// ---------- dispatch: wave per expert, stable-order rank scan ----------
__global__ __launch_bounds__(1024) void dispatch_k(const int* __restrict__ tki,
                                                   const float* __restrict__ tkw,
                                                   int* __restrict__ stok,
                                                   float* __restrict__ sw){
  const int e = blockIdx.x*16 + (threadIdx.x >> 6);
  const int lane = threadIdx.x & 63;
  int base = 0;
  for (int it = 0; it < (T_TOK*TOPK)/64; ++it){
    if (base >= CAP) break;
    int idx = it*64 + lane;
    int ex = tki[idx];
    bool m = (ex == e);
    unsigned long long mk = __ballot(m);
    int pos = base + __popcll(mk & ((1ull << lane) - 1ull));
    if (m && pos < CAP){
      stok[e*CAP + pos] = idx >> 2;
      sw[e*CAP + pos]   = tkw[idx];
    }
    base += __popcll(mk);
  }
}

// ---------- MFMA GEMM, fragment-major conflict-free LDS ----------
// GU=1: H(bf16) = silu(A@Bg)*(A@Bu), 32+32 cols/block
// GU=0: out(f32) = A@B (EXPERT: scaled atomic scatter), 64 cols/block
// EXPERT: A rows gathered via stok (GU) or slot rows; B layout [K,N]. else B [N,K].
// LDS planes: 16 rows(cols) x 32k as 1KB, chunk index == lane -> all LDS ops
// are uniform_base + lane*16 (conflict-free; matches global_load_lds layout).
template<int EXPERT, int GU>
__global__ __launch_bounds__(256, 4)
void gemm3_k(const unsigned short* __restrict__ Ab,
             const float* __restrict__ B0, const float* __restrict__ B1,
             void* __restrict__ Co,
             const int* __restrict__ stok, const float* __restrict__ sw){
  constexpr int BM   = EXPERT ? 160 : 128;
  constexpr int APL  = BM/16;                 // A planes (10 / 8)
  constexpr int FM   = APL/2;                 // A frags per wave
  constexpr int KK   = GU ? DIM : (EXPERT ? ISZ : ISH);
  constexpr int LDB  = EXPERT ? (GU ? ISZ : DIM) : KK;
  constexpr int LDC  = GU ? (EXPERT ? ISZ : ISH) : DIM;
  constexpr int NBc  = (!EXPERT && GU) ? 64 : 32;   // n-blocks per group
  constexpr int NT   = KK/32;
  constexpr int NAIT = (APL+3)/4;

  __shared__ uint4 Alds[2][APL*64];
  __shared__ uint4 Blds[2][4*64];

  const int tid  = threadIdx.x;
  const int lane = tid & 63, wid = tid >> 6;

  // bijective XCD swizzle: all n-blocks of one group (expert / m-row block)
  // land on one XCD -> shared A-tile stays L2-resident
  const int bid  = blockIdx.x;
  const int xcd  = bid & 7, seq = bid >> 3;
  const int grp  = xcd + 8*(seq/NBc);
  const int nblk = seq % NBc;
  const int e    = grp;
  const int mb   = EXPERT ? grp*CAP : grp*BM;
  const int nb   = nblk * (GU ? 32 : 64);

  // ---- A gather pointers (per-lane, plane-permuted source) ----
  const unsigned short* aptr[NAIT];
  #pragma unroll
  for (int i = 0; i < NAIT; ++i){
    int p = wid + i*4; if (p >= APL) p = 0;
    int row = p*16 + (lane & 15);
    int tr;
    if constexpr (EXPERT && GU) tr = stok[mb + row];
    else                        tr = mb + row;
    aptr[i] = Ab + (size_t)tr*KK + (lane >> 4)*8;
  }
  auto stageA = [&](int k0, int buf){
    #pragma unroll
    for (int i = 0; i < NAIT; ++i){
      int p = wid + i*4;
      if (i*4 + 3 < APL || p < APL)
        GLOAD16(aptr[i] + k0, (char*)&Alds[buf][0] + p*1024);
    }
  };

  // ---- B staging: wave `wid` owns plane `wid`; chunk == lane ----
  const int bpl = wid;
  const float* bbase;
  {
    int mat = GU ? (bpl >> 1) : 0;
    int pc  = GU ? (bpl & 1)  : bpl;
    const float* s = (GU && mat) ? B1 : B0;
    int col = nb + pc*16 + (lane & 15);
    if constexpr (EXPERT)
      bbase = s + (size_t)e*KK*LDB + col;          // + (k0 + kc*8)*LDB per step
    else
      bbase = s + (size_t)col*LDB + (lane >> 4)*8; // + k0 per step
  }
  float bf_[8];
  auto loadB = [&](int k0){
    if constexpr (EXPERT){
      const float* q = bbase + (size_t)(k0 + (lane >> 4)*8)*LDB;
      #pragma unroll
      for (int j = 0; j < 8; ++j) bf_[j] = q[(size_t)j*LDB];
    } else {
      const float* q = bbase + k0;
      *(float4*)&bf_[0] = *(const float4*)q;
      *(float4*)&bf_[4] = *(const float4*)(q + 4);
    }
  };
  auto writeB = [&](int buf){
    uint4 v;
    v.x = f2bf(bf_[0]) | (f2bf(bf_[1]) << 16);
    v.y = f2bf(bf_[2]) | (f2bf(bf_[3]) << 16);
    v.z = f2bf(bf_[4]) | (f2bf(bf_[5]) << 16);
    v.w = f2bf(bf_[6]) | (f2bf(bf_[7]) << 16);
    *(uint4*)((char*)&Blds[buf][0] + bpl*1024 + lane*16) = v;
  };

  const int wn  = wid & 1;
  const int wmp = (wid >> 1) * FM;
  const int pl0 = GU ? wn       : 2*wn;
  const int pl1 = GU ? (2 + wn) : (2*wn + 1);

  f32x4 acc[FM][2];
  #pragma unroll
  for (int i = 0; i < FM; ++i){ acc[i][0] = f32x4{0,0,0,0}; acc[i][1] = f32x4{0,0,0,0}; }

  stageA(0, 0);
  loadB(0);
  writeB(0);
  __syncthreads();

  #pragma unroll 2
  for (int t = 0; t < NT; ++t){
    const int cur = t & 1;
    const bool pf = (t + 1 < NT);
    if (pf){ stageA((t+1)*32, cur^1); loadB((t+1)*32); }
    const char* Al = (const char*)&Alds[cur][0];
    const char* Bl = (const char*)&Blds[cur][0];
    bf16x8 af[FM], b0, b1;
    #pragma unroll
    for (int i = 0; i < FM; ++i)
      af[i] = *(const bf16x8*)(Al + (wmp + i)*1024 + lane*16);
    b0 = *(const bf16x8*)(Bl + pl0*1024 + lane*16);
    b1 = *(const bf16x8*)(Bl + pl1*1024 + lane*16);
    #pragma unroll
    for (int i = 0; i < FM; ++i){
      acc[i][0] = __builtin_amdgcn_mfma_f32_16x16x32_bf16(af[i], b0, acc[i][0], 0, 0, 0);
      acc[i][1] = __builtin_amdgcn_mfma_f32_16x16x32_bf16(af[i], b1, acc[i][1], 0, 0, 0);
    }
    if (pf) writeB(cur^1);
    __syncthreads();
  }

  // ---- epilogue ----
  const int r16 = lane & 15, rg = (lane >> 4) * 4;
  #pragma unroll
  for (int i = 0; i < FM; ++i){
    #pragma unroll
    for (int r = 0; r < 4; ++r){
      const int m = wmp*16 + i*16 + rg + r;
      if constexpr (GU){
        float g = acc[i][0][r], u = acc[i][1][r];
        float h = g / (1.f + __expf(-g)) * u;
        int c = nb + wn*16 + r16;
        ((unsigned short*)Co)[(size_t)(mb + m)*LDC + c] = (unsigned short)f2bf(h);
      } else if constexpr (EXPERT){
        const int slot = mb + m;
        float w = sw[slot];
        if (w != 0.f){
          int tok = stok[slot];
          #pragma unroll
          for (int j = 0; j < 2; ++j){
            int c = nb + (2*wn + j)*16 + r16;
            atomicAdd(&((float*)Co)[(size_t)tok*LDC + c], w * acc[i][j][r]);
          }
        }
      } else {
        #pragma unroll
        for (int j = 0; j < 2; ++j){
          int c = nb + (2*wn + j)*16 + r16;
          ((float*)Co)[(size_t)(mb + m)*LDC + c] = acc[i][j][r];
        }
      }
    }
  }
}

extern "C" void kernel_launch(void* const* d_in, const int* in_sizes, int n_in,
                              void* d_out, int out_size, void* d_ws, size_t ws_size,
                              hipStream_t stream){
  const float* x  = (const float*)d_in[0];
  const float* rw = (const float*)d_in[1];
  const float* eb = (const float*)d_in[2];
  const float* wg = (const float*)d_in[3];
  const float* wu = (const float*)d_in[4];
  const float* wd = (const float*)d_in[5];
  const float* sg = (const float*)d_in[6];
  const float* su = (const float*)d_in[7];
  const float* sd = (const float*)d_in[8];
  float* out = (float*)d_out;

  char* ws = (char*)d_ws;
  unsigned short* xbf = (unsigned short*)ws; ws += (size_t)T_TOK*DIM*2;
  unsigned short* hsh = (unsigned short*)ws; ws += (size_t)T_TOK*ISH*2;   // shared silu(g)*u
  unsigned short* hex = (unsigned short*)ws; ws += (size_t)ECAP*ISZ*2;    // expert silu(g)*u
  int*   tki  = (int*)ws;   ws += (size_t)T_TOK*TOPK*4;
  float* tkw  = (float*)ws; ws += (size_t)T_TOK*TOPK*4;
  int*   stok = (int*)ws;   ws += (size_t)ECAP*4;
  float* sw   = (float*)ws; ws += (size_t)ECAP*4;

  // x -> bf16; router; dispatch
  cvt_k<<<(T_TOK*DIM/8)/256, 256, 0, stream>>>(x, xbf, T_TOK*DIM/8);
  router_k<<<T_TOK/4, 256, 0, stream>>>(x, rw, eb, tki, tkw);
  hipMemsetAsync(stok, 0, (size_t)ECAP*8, stream);   // stok + sw contiguous
  dispatch_k<<<2, 1024, 0, stream>>>(tki, tkw, stok, sw);

  // shared MLP: fused gate+up+silu -> h ; down -> out (plain store initializes d_out)
  gemm3_k<0,1><<<2048, 256, 0, stream>>>(xbf, sg, su, hsh, nullptr, nullptr);
  gemm3_k<0,0><<<1024, 256, 0, stream>>>(hsh, sd, nullptr, out, nullptr, nullptr);

  // routed experts: fused gate+up+silu -> h ; down -> atomic scaled scatter into out
  gemm3_k<1,1><<<1024, 256, 0, stream>>>(xbf, wg, wu, hex, stok, sw);
  gemm3_k<1,0><<<1024, 256, 0, stream>>>(hex, wd, nullptr, out, stok, sw);
}

// Round 4
// 775.260 us; speedup vs baseline: 1.0708x; 1.0708x over previous
//
#include <hip/hip_runtime.h>
#include <math.h>

// ---------- config ----------
#define T_TOK 4096
#define DIM   2048
#define NEXP  32
#define TOPK  4
#define CAP   160          // ceil(1.25*4096/32)
#define ECAP  (NEXP*CAP)   // 5120
#define ISZ   1024         // moe intermediate
#define ISH   2048         // shared intermediate (I*NSH)

typedef short bf16x8 __attribute__((ext_vector_type(8)));
typedef float f32x4  __attribute__((ext_vector_type(4)));

__device__ __forceinline__ unsigned int f2bf(float f){
  union { float f; unsigned int u; } v; v.f = f;
  return (v.u + 0x7fffu + ((v.u >> 16) & 1u)) >> 16;   // RNE
}

// async global->LDS, 16B/lane; LDS base wave-uniform (HW adds lane*16), global addr per-lane
#define GLOAD16(g, l) __builtin_amdgcn_global_load_lds( \
    (const __attribute__((address_space(1))) unsigned int*)(g), \
    (__attribute__((address_space(3))) unsigned int*)(l), 16, 0, 0)

// ---------- fp32 -> bf16 convert ----------
__global__ __launch_bounds__(256) void cvt_k(const float* __restrict__ in,
                                             unsigned short* __restrict__ out, int n8){
  int i = blockIdx.x*256 + threadIdx.x;
  if (i >= n8) return;
  const float4 a = *(const float4*)&in[(size_t)i*8];
  const float4 b = *(const float4*)&in[(size_t)i*8 + 4];
  uint4 v;
  v.x = f2bf(a.x) | (f2bf(a.y) << 16);
  v.y = f2bf(a.z) | (f2bf(a.w) << 16);
  v.z = f2bf(b.x) | (f2bf(b.y) << 16);
  v.w = f2bf(b.z) | (f2bf(b.w) << 16);
  *(uint4*)&out[(size_t)i*8] = v;
}

// ---------- router: fp64 logits, exact top-k semantics ----------
__global__ __launch_bounds__(256) void router_k(const float* __restrict__ x,
                                                const float* __restrict__ rw,
                                                const float* __restrict__ eb,
                                                int* __restrict__ tki,
                                                float* __restrict__ tkw){
  __shared__ float  xs[4][DIM];
  __shared__ double ssh[4][NEXP];
  const int tb = blockIdx.x * 4;
  const int tid = threadIdx.x;
  for (int i = tid; i < 4*(DIM/4); i += 256){
    int t = i >> 9, c = (i & 511) << 2;
    *(float4*)&xs[t][c] = *(const float4*)&x[(size_t)(tb + t)*DIM + c];
  }
  __syncthreads();
  const int lane = tid & 63, wv = tid >> 6;
  for (int ei = 0; ei < 8; ++ei){
    int e = wv*8 + ei;
    double a0=0, a1=0, a2=0, a3=0;
    for (int d = lane; d < DIM; d += 64){
      double w = (double)rw[(size_t)e*DIM + d];
      a0 += (double)xs[0][d] * w;
      a1 += (double)xs[1][d] * w;
      a2 += (double)xs[2][d] * w;
      a3 += (double)xs[3][d] * w;
    }
    for (int off = 32; off; off >>= 1){
      a0 += __shfl_down(a0, off);
      a1 += __shfl_down(a1, off);
      a2 += __shfl_down(a2, off);
      a3 += __shfl_down(a3, off);
    }
    if (lane == 0){ ssh[0][e]=a0; ssh[1][e]=a1; ssh[2][e]=a2; ssh[3][e]=a3; }
  }
  __syncthreads();
  if (tid < 4){
    const int t = tid;
    double s[NEXP], sc[NEXP];
    for (int e = 0; e < NEXP; ++e){
      double sig = 1.0 / (1.0 + exp(-ssh[t][e]));
      s[e] = sig; sc[e] = sig + (double)eb[e];
    }
    double gsc[8];
    for (int g = 0; g < 8; ++g){
      double b0=sc[g*4],b1=sc[g*4+1],b2=sc[g*4+2],b3=sc[g*4+3];
      double h1=fmax(b0,b1), l1=fmin(b0,b1);
      double h2=fmax(b2,b3), l2=fmin(b2,b3);
      double top = fmax(h1,h2);
      double sec = fmax(fmin(h1,h2), (h1 >= h2) ? l1 : l2);
      gsc[g] = top + sec;
    }
    int gsel = 0;
    for (int r = 0; r < 3; ++r){
      int bi = -1; double bv = -1e300;
      for (int g = 0; g < 8; ++g)
        if (!((gsel >> g) & 1) && gsc[g] > bv){ bv = gsc[g]; bi = g; }
      gsel |= 1 << bi;
    }
    double mval[NEXP];
    for (int e = 0; e < NEXP; ++e)
      mval[e] = ((gsel >> (e >> 2)) & 1) ? sc[e] : 0.0;
    int idx4[4]; double wsum = 0.0, wv4[4];
    for (int r = 0; r < 4; ++r){
      int bi = -1; double bv = -1e300;
      for (int e = 0; e < NEXP; ++e)
        if (mval[e] > bv){ bv = mval[e]; bi = e; }
      idx4[r] = bi; mval[bi] = -1e300;
      wv4[r] = s[bi]; wsum += wv4[r];
    }
    const int gt = tb + t;
    for (int r = 0; r < 4; ++r){
      tki[gt*4 + r] = idx4[r];
      tkw[gt*4 + r] = (float)(wv4[r] / (wsum + 1e-20) * 2.5);
    }
  }
}

// ---------- dispatch: wave per expert, stable-order rank scan ----------
__global__ __launch_bounds__(1024) void dispatch_k(const int* __restrict__ tki,
                                                   const float* __restrict__ tkw,
                                                   int* __restrict__ stok,
                                                   float* __restrict__ sw){
  const int e = blockIdx.x*16 + (threadIdx.x >> 6);
  const int lane = threadIdx.x & 63;
  int base = 0;
  for (int it = 0; it < (T_TOK*TOPK)/64; ++it){
    if (base >= CAP) break;
    int idx = it*64 + lane;
    int ex = tki[idx];
    bool m = (ex == e);
    unsigned long long mk = __ballot(m);
    int pos = base + __popcll(mk & ((1ull << lane) - 1ull));
    if (m && pos < CAP){
      stok[e*CAP + pos] = idx >> 2;
      sw[e*CAP + pos]   = tkw[idx];
    }
    base += __popcll(mk);
  }
}

// ---------- MFMA GEMM, fragment-major conflict-free LDS ----------
// shared GU : H(bf16)=silu(A@Bg)*(A@Bu), 64+64 cols/block (8 B-planes)
// expert GU : H(bf16)=silu(A@Bg)*(A@Bu), 32+32 cols/block (4 B-planes), A gathered
// down      : out(f32)=A@B, 64 cols/block (EXPERT: scaled atomic scatter)
// Block order: shared -> same-n consecutive (weight-slice sharing);
//              expert -> same-expert consecutive (A-tile sharing; weights n-partitioned)
// LDS planes: 16 rows(cols) x 32k = 1KB, chunk == lane -> all LDS ops uniform_base+lane*16.
template<int EXPERT, int GU>
__global__ __launch_bounds__(256, 4)
void gemm4_k(const unsigned short* __restrict__ Ab,
             const float* __restrict__ B0, const float* __restrict__ B1,
             void* __restrict__ Co,
             const int* __restrict__ stok, const float* __restrict__ sw){
  constexpr int BM   = EXPERT ? 160 : 128;
  constexpr int APL  = BM/16;                  // A planes (10 / 8)
  constexpr int FM   = APL/2;                  // A frags per wave
  constexpr int KK   = GU ? DIM : (EXPERT ? ISZ : ISH);
  constexpr int LDB  = EXPERT ? (GU ? ISZ : DIM) : KK;
  constexpr int LDC  = GU ? (EXPERT ? ISZ : ISH) : DIM;
  constexpr int BPL  = (!EXPERT && GU) ? 8 : 4;   // B planes
  constexpr int NPW  = BPL/4;                  // B planes staged per wave
  constexpr int NBF  = BPL/2;                  // B frags per wave (wave covers half the planes)
  constexpr int NW   = GU ? (EXPERT ? 32 : 64) : 64;   // output cols per block
  constexpr int NT   = KK/32;
  constexpr int NAIT = (APL+3)/4;

  __shared__ uint4 Alds[2][APL*64];
  __shared__ uint4 Blds[2][BPL*64];

  const int tid  = threadIdx.x;
  const int lane = tid & 63, wid = tid >> 6;

  // block mapping (32 groups in both cases)
  const int bid  = blockIdx.x;
  int grp, nblk;
  if constexpr (EXPERT){ grp = bid >> 5; nblk = bid & 31; }  // same-expert adjacent
  else                 { grp = bid & 31; nblk = bid >> 5; }  // same-n adjacent
  const int e  = grp;
  const int mb = EXPERT ? grp*CAP : grp*BM;
  const int nb = nblk * NW;

  // ---- A gather pointers (per-lane, plane-permuted source) ----
  const unsigned short* aptr[NAIT];
  #pragma unroll
  for (int i = 0; i < NAIT; ++i){
    int p = wid + i*4; if (p >= APL) p = 0;
    int row = p*16 + (lane & 15);
    int tr;
    if constexpr (EXPERT && GU) tr = stok[mb + row];
    else                        tr = mb + row;
    aptr[i] = Ab + (size_t)tr*KK + (lane >> 4)*8;
  }
  auto stageA = [&](int k0, int buf){
    #pragma unroll
    for (int i = 0; i < NAIT; ++i){
      int p = wid + i*4;
      if (i*4 + 3 < APL || p < APL)
        GLOAD16(aptr[i] + k0, (char*)&Alds[buf][0] + p*1024);
    }
  };

  // ---- B staging: wave stages planes {wid (+4)}; chunk == lane ----
  const float* bbase[NPW];
  #pragma unroll
  for (int pi = 0; pi < NPW; ++pi){
    int p = wid + pi*4;
    int mat, colg;
    if constexpr (!EXPERT && GU){ mat = p >> 2; colg = p & 3; }
    else if constexpr (GU)      { mat = p >> 1; colg = p & 1; }
    else                        { mat = 0;      colg = p;     }
    const float* s = mat ? B1 : B0;
    int col = nb + colg*16 + (lane & 15);
    if constexpr (EXPERT) bbase[pi] = s + (size_t)e*KK*LDB + col;
    else                  bbase[pi] = s + (size_t)col*LDB + (lane >> 4)*8;
  }
  float bf_[NPW][8];
  auto loadB = [&](int k0){
    #pragma unroll
    for (int pi = 0; pi < NPW; ++pi){
      if constexpr (EXPERT){
        const float* q = bbase[pi] + (size_t)(k0 + (lane >> 4)*8)*LDB;
        #pragma unroll
        for (int j = 0; j < 8; ++j) bf_[pi][j] = q[(size_t)j*LDB];
      } else {
        const float* q = bbase[pi] + k0;
        *(float4*)&bf_[pi][0] = *(const float4*)q;
        *(float4*)&bf_[pi][4] = *(const float4*)(q + 4);
      }
    }
  };
  auto writeB = [&](int buf){
    #pragma unroll
    for (int pi = 0; pi < NPW; ++pi){
      int p = wid + pi*4;
      uint4 v;
      v.x = f2bf(bf_[pi][0]) | (f2bf(bf_[pi][1]) << 16);
      v.y = f2bf(bf_[pi][2]) | (f2bf(bf_[pi][3]) << 16);
      v.z = f2bf(bf_[pi][4]) | (f2bf(bf_[pi][5]) << 16);
      v.w = f2bf(bf_[pi][6]) | (f2bf(bf_[pi][7]) << 16);
      *(uint4*)((char*)&Blds[buf][0] + p*1024 + lane*16) = v;
    }
  };

  // ---- compute-side plane assignment per wave ----
  const int wn  = wid & 1;
  const int wmp = (wid >> 1) * FM;
  int bpls[NBF];
  if constexpr (!EXPERT && GU){
    bpls[0] = 2*wn; bpls[1] = 2*wn + 1; bpls[2] = 4 + 2*wn; bpls[3] = 5 + 2*wn;
  } else if constexpr (GU){
    bpls[0] = wn; bpls[1] = 2 + wn;
  } else {
    bpls[0] = 2*wn; bpls[1] = 2*wn + 1;
  }

  f32x4 acc[FM][NBF];
  #pragma unroll
  for (int i = 0; i < FM; ++i)
    #pragma unroll
    for (int j = 0; j < NBF; ++j) acc[i][j] = f32x4{0,0,0,0};

  stageA(0, 0);
  loadB(0);
  writeB(0);
  __syncthreads();

  #pragma unroll 2
  for (int t = 0; t < NT; ++t){
    const int cur = t & 1;
    const bool pf = (t + 1 < NT);
    if (pf){ stageA((t+1)*32, cur^1); loadB((t+1)*32); }
    const char* Al = (const char*)&Alds[cur][0];
    const char* Bl = (const char*)&Blds[cur][0];
    bf16x8 af[FM], bfr[NBF];
    #pragma unroll
    for (int i = 0; i < FM; ++i)
      af[i] = *(const bf16x8*)(Al + (wmp + i)*1024 + lane*16);
    #pragma unroll
    for (int j = 0; j < NBF; ++j)
      bfr[j] = *(const bf16x8*)(Bl + bpls[j]*1024 + lane*16);
    #pragma unroll
    for (int i = 0; i < FM; ++i)
      #pragma unroll
      for (int j = 0; j < NBF; ++j)
        acc[i][j] = __builtin_amdgcn_mfma_f32_16x16x32_bf16(af[i], bfr[j], acc[i][j], 0, 0, 0);
    if (pf) writeB(cur^1);
    __syncthreads();
  }

  // ---- epilogue ----
  const int r16 = lane & 15, rg = (lane >> 4) * 4;
  #pragma unroll
  for (int i = 0; i < FM; ++i){
    #pragma unroll
    for (int r = 0; r < 4; ++r){
      const int m = wmp*16 + i*16 + rg + r;
      if constexpr (GU && !EXPERT){
        #pragma unroll
        for (int jj = 0; jj < 2; ++jj){
          float g = acc[i][jj][r], u = acc[i][2+jj][r];
          float h = g / (1.f + __expf(-g)) * u;
          int c = nb + (2*wn + jj)*16 + r16;
          ((unsigned short*)Co)[(size_t)(mb + m)*LDC + c] = (unsigned short)f2bf(h);
        }
      } else if constexpr (GU){
        float g = acc[i][0][r], u = acc[i][1][r];
        float h = g / (1.f + __expf(-g)) * u;
        int c = nb + wn*16 + r16;
        ((unsigned short*)Co)[(size_t)(mb + m)*LDC + c] = (unsigned short)f2bf(h);
      } else if constexpr (EXPERT){
        const int slot = mb + m;
        float w = sw[slot];
        if (w != 0.f){
          int tok = stok[slot];
          #pragma unroll
          for (int j = 0; j < 2; ++j){
            int c = nb + (2*wn + j)*16 + r16;
            atomicAdd(&((float*)Co)[(size_t)tok*LDC + c], w * acc[i][j][r]);
          }
        }
      } else {
        #pragma unroll
        for (int j = 0; j < 2; ++j){
          int c = nb + (2*wn + j)*16 + r16;
          ((float*)Co)[(size_t)(mb + m)*LDC + c] = acc[i][j][r];
        }
      }
    }
  }
}

extern "C" void kernel_launch(void* const* d_in, const int* in_sizes, int n_in,
                              void* d_out, int out_size, void* d_ws, size_t ws_size,
                              hipStream_t stream){
  const float* x  = (const float*)d_in[0];
  const float* rw = (const float*)d_in[1];
  const float* eb = (const float*)d_in[2];
  const float* wg = (const float*)d_in[3];
  const float* wu = (const float*)d_in[4];
  const float* wd = (const float*)d_in[5];
  const float* sg = (const float*)d_in[6];
  const float* su = (const float*)d_in[7];
  const float* sd = (const float*)d_in[8];
  float* out = (float*)d_out;

  char* ws = (char*)d_ws;
  unsigned short* xbf = (unsigned short*)ws; ws += (size_t)T_TOK*DIM*2;
  unsigned short* hsh = (unsigned short*)ws; ws += (size_t)T_TOK*ISH*2;   // shared silu(g)*u
  unsigned short* hex = (unsigned short*)ws; ws += (size_t)ECAP*ISZ*2;    // expert silu(g)*u
  int*   tki  = (int*)ws;   ws += (size_t)T_TOK*TOPK*4;
  float* tkw  = (float*)ws; ws += (size_t)T_TOK*TOPK*4;
  int*   stok = (int*)ws;   ws += (size_t)ECAP*4;
  float* sw   = (float*)ws; ws += (size_t)ECAP*4;

  // x -> bf16; router; dispatch
  cvt_k<<<(T_TOK*DIM/8)/256, 256, 0, stream>>>(x, xbf, T_TOK*DIM/8);
  router_k<<<T_TOK/4, 256, 0, stream>>>(x, rw, eb, tki, tkw);
  hipMemsetAsync(stok, 0, (size_t)ECAP*8, stream);   // stok + sw contiguous
  dispatch_k<<<2, 1024, 0, stream>>>(tki, tkw, stok, sw);

  // shared MLP: fused gate+up+silu -> h ; down -> out (plain store initializes d_out)
  gemm4_k<0,1><<<1024, 256, 0, stream>>>(xbf, sg, su, hsh, nullptr, nullptr);
  gemm4_k<0,0><<<1024, 256, 0, stream>>>(hsh, sd, nullptr, out, nullptr, nullptr);

  // routed experts: fused gate+up+silu -> h ; down -> atomic scaled scatter into out
  gemm4_k<1,1><<<1024, 256, 0, stream>>>(xbf, wg, wu, hex, stok, sw);
  gemm4_k<1,0><<<1024, 256, 0, stream>>>(hex, wd, nullptr, out, stok, sw);
}